// Round 20
// baseline (478.939 us; speedup 1.0000x reference)
//
#include <hip/hip_runtime.h>
#include <hip/hip_bf16.h>

#define D_  1536
#define H_  16
#define HD_ 96
#define NX_ 2048
#define NY_ 256
#define NT_ 2304
#define FF_ 6144
#define EPS_ 1e-6f

typedef unsigned short u16;
typedef unsigned int   u32;
typedef short short8 __attribute__((ext_vector_type(8)));
typedef float f32x4  __attribute__((ext_vector_type(4)));
typedef unsigned short u16x4 __attribute__((ext_vector_type(4)));

__device__ __forceinline__ u16 f2bf(float f){
    u32 u = __float_as_uint(f);
    return (u16)((u + 0x7fffu + ((u >> 16) & 1u)) >> 16);   // RNE
}
__device__ __forceinline__ float bf2f(u16 h){ return __uint_as_float(((u32)h) << 16); }

__device__ __forceinline__ void gll16(const void* g, void* l){
    __builtin_amdgcn_global_load_lds(
        (const __attribute__((address_space(1))) unsigned int*)g,
        (__attribute__((address_space(3))) unsigned int*)l, 16, 0, 0);
}

// ---------------------------------------------------------------- weight transpose
__global__ __launch_bounds__(256) void transpose_k(
    const float* __restrict__ Wx, const float* __restrict__ Wy,
    u16* __restrict__ Ox, u16* __restrict__ Oy, int K, int N)
{
    const float* W = blockIdx.y ? Wy : Wx;
    u16* O = blockIdx.y ? Oy : Ox;
    int tn_cnt = N >> 5;
    int tk = blockIdx.x / tn_cnt, tn = blockIdx.x % tn_cnt;
    __shared__ float tile[32][33];
    int t = threadIdx.x;
    {
        int k = t >> 3, n4 = (t & 7) * 4;
        float4 v = *(const float4*)&W[(size_t)(tk*32 + k) * N + tn*32 + n4];
        tile[k][n4+0] = v.x; tile[k][n4+1] = v.y;
        tile[k][n4+2] = v.z; tile[k][n4+3] = v.w;
    }
    __syncthreads();
    {
        int n = t >> 3, k4 = (t & 7) * 4;
        u16x4 r;
        #pragma unroll
        for (int i = 0; i < 4; i++) r[i] = f2bf(tile[k4+i][n]);
        *(u16x4*)&O[(size_t)(tn*32 + n) * K + tk*32 + k4] = r;
    }
}

// ---------------------------------------------------------------- mod GEMV (split-K x16)
__global__ __launch_bounds__(256) void modvec2_k(
    const float* __restrict__ t_in,
    const float* __restrict__ w_mod_x, const float* __restrict__ w_mod_y,
    float* __restrict__ pbuf)
{
    int part = blockIdx.y;
    int j = blockIdx.x * 256 + threadIdx.x;
    __shared__ float st[96];
    int k0 = part * 96;
    if (threadIdx.x < 96){
        float v = t_in[k0 + threadIdx.x];
        st[threadIdx.x] = v / (1.f + __expf(-v));
    }
    __syncthreads();
    const float* W; int col;
    if (j < 6*D_){ W = w_mod_x; col = j; }
    else         { W = w_mod_y; col = j - 6*D_; }
    const float* wp = W + (size_t)k0 * (6*D_) + col;
    float acc = 0.f;
    #pragma unroll 8
    for (int k = 0; k < 96; k++)
        acc += st[k] * wp[(size_t)k * (6*D_)];
    pbuf[(size_t)part * 18432 + j] = acc;
}

__global__ __launch_bounds__(256) void reducemod_k(
    const float* __restrict__ pbuf,
    const float* __restrict__ b_mod_x, const float* __restrict__ b_mod_y,
    float* __restrict__ modx, float* __restrict__ mody)
{
    int j = blockIdx.x * 256 + threadIdx.x;
    float acc = (j < 6*D_) ? b_mod_x[j] : b_mod_y[j - 6*D_];
    #pragma unroll
    for (int p = 0; p < 16; p++)
        acc += pbuf[(size_t)p * 18432 + j];
    if (j < 6*D_) modx[j] = acc;
    else          mody[j - 6*D_] = acc;
}

// ---------------------------------------------------------------- LN + modulate -> bf16
__global__ __launch_bounds__(256) void lnmod_k(
    const float* __restrict__ inx, const float* __restrict__ iny,
    const float* __restrict__ modx, const float* __restrict__ mody,
    int shoff, u16* __restrict__ out)
{
    int row = blockIdx.x, t = threadIdx.x;
    const float* in; const float* mod;
    if (row < NX_){ in = inx + (size_t)row * D_;        mod = modx; }
    else          { in = iny + (size_t)(row-NX_) * D_;  mod = mody; }
    const float* sh = mod + shoff;
    const float* sc = mod + shoff + D_;
    float vals[6]; float s = 0.f, ss = 0.f;
    #pragma unroll
    for (int j = 0; j < 6; j++){
        float v = in[t + j*256];
        vals[j] = v; s += v; ss += v*v;
    }
    for (int mask = 1; mask < 64; mask <<= 1){
        s  += __shfl_xor(s,  mask);
        ss += __shfl_xor(ss, mask);
    }
    __shared__ float red[2][4];
    int wave = t >> 6, lane = t & 63;
    if (lane == 0){ red[0][wave] = s; red[1][wave] = ss; }
    __syncthreads();
    s  = red[0][0] + red[0][1] + red[0][2] + red[0][3];
    ss = red[1][0] + red[1][1] + red[1][2] + red[1][3];
    float mean = s * (1.f / D_);
    float var  = ss * (1.f / D_) - mean * mean;
    float inv  = rsqrtf(var + EPS_);
    #pragma unroll
    for (int j = 0; j < 6; j++){
        int c = t + j*256;
        float z = (vals[j] - mean) * inv;
        z = z * (1.f + sc[c]) + sh[c];
        out[(size_t)row * D_ + c] = f2bf(z);
    }
}

// ---------------------------------------------------------------- GEMM 256x256, BK=64
template<int MODE>
__global__ __launch_bounds__(512, 2) void gemm3_k(
    const u16* __restrict__ A,
    const u16* __restrict__ BTx, const u16* __restrict__ BTy,
    const float* __restrict__ biasx, const float* __restrict__ biasy,
    const u16* __restrict__ hmul,
    u16* __restrict__ outB, int ldo,
    int K, int mb, int nb)
{
    __shared__ u16 As[2][256*64];
    __shared__ u16 Bs[2][256*64];
    int nwg = mb * nb;
    int bid = blockIdx.x;
    int q = nwg >> 3, r = nwg & 7, xcd = bid & 7;    // bijective XCD swizzle (m204)
    int wgid = (xcd < r ? xcd*(q+1) : r*(q+1) + (xcd - r)*q) + (bid >> 3);
    int bm = wgid % mb, bn = wgid / mb;
    int sel = (bm == mb - 1);
    int row0 = bm * 256, col0 = bn * 256;
    const u16* Bt = sel ? BTy : BTx;

    int t = threadIdx.x, wid = t >> 6, lane = t & 63;
    int lrow = lane & 15, lgrp = lane >> 4;
    int wr = (wid >> 2) * 128, wc = (wid & 3) * 64;

    const char* Ab = (const char*)(A  + (size_t)row0 * K);
    const char* Bb = (const char*)(Bt + (size_t)col0 * K);
    u32 offG[4], offL[4];
    #pragma unroll
    for (int i = 0; i < 4; i++){
        int rr = i*64 + (t >> 3);
        int cc = (t & 7) ^ (rr & 7);
        offG[i] = (u32)(rr * K + cc * 8) * 2;
        offL[i] = (u32)(i*8192 + t*16);
    }

    #define STAGEG(bsel, kb) do{                                                  \
        _Pragma("unroll")                                                         \
        for (int i = 0; i < 4; i++)                                               \
            gll16(Ab + (offG[i] + (kb)), (char*)As[bsel] + offL[i]);              \
        _Pragma("unroll")                                                         \
        for (int i = 0; i < 4; i++)                                               \
            gll16(Bb + (offG[i] + (kb)), (char*)Bs[bsel] + offL[i]);              \
    } while(0)

    f32x4 acc[8][4];
    #pragma unroll
    for (int i = 0; i < 8; i++)
        #pragma unroll
        for (int j = 0; j < 4; j++) acc[i][j] = (f32x4){0.f,0.f,0.f,0.f};

    int nt = K >> 6;
    STAGEG(0, 0);

    for (int tt = 0; tt < nt; tt++){
        const u16* Ac = As[tt & 1];
        const u16* Bc = Bs[tt & 1];
        if (tt + 1 < nt){
            STAGEG((tt + 1) & 1, (u32)(tt + 1) * 128);
            asm volatile("s_waitcnt vmcnt(8)" ::: "memory");
        } else {
            asm volatile("s_waitcnt vmcnt(0)" ::: "memory");
        }
        __builtin_amdgcn_sched_barrier(0);
        __builtin_amdgcn_s_barrier();
        __builtin_amdgcn_sched_barrier(0);
        #pragma unroll
        for (int kk = 0; kk < 2; kk++){
            int pc = ((kk*4 + lgrp) ^ (lrow & 7)) * 8;
            short8 bf[4];
            #pragma unroll
            for (int ni = 0; ni < 4; ni++)
                bf[ni] = *(const short8*)&Bc[(wc + ni*16 + lrow)*64 + pc];
            #pragma unroll
            for (int mi = 0; mi < 8; mi++){
                short8 af = *(const short8*)&Ac[(wr + mi*16 + lrow)*64 + pc];
                #pragma unroll
                for (int ni = 0; ni < 4; ni++)
                    acc[mi][ni] = __builtin_amdgcn_mfma_f32_16x16x32_bf16(
                                      af, bf[ni], acc[mi][ni], 0, 0, 0);
            }
        }
        asm volatile("s_waitcnt lgkmcnt(0)" ::: "memory");
        __builtin_amdgcn_sched_barrier(0);
        __builtin_amdgcn_s_barrier();
        __builtin_amdgcn_sched_barrier(0);
    }
    #undef STAGEG

    const float* biasp = sel ? biasy : biasx;
    #pragma unroll
    for (int mi = 0; mi < 8; mi++){
        #pragma unroll
        for (int ni = 0; ni < 4; ni++){
            #pragma unroll
            for (int rr = 0; rr < 4; rr++){
                int gr = row0 + wr + mi*16 + lgrp*4 + rr;
                int gc = col0 + wc + ni*16 + lrow;
                float v = acc[mi][ni][rr];
                size_t oi = (size_t)gr * ldo + gc;
                if (MODE == 0)      outB[oi] = f2bf(v + biasp[gc]);
                else if (MODE == 2) outB[oi] = f2bf(v / (1.f + __expf(-v)));
                else if (MODE == 3) outB[oi] = f2bf(bf2f(hmul[oi]) * v);
            }
        }
    }
}

// ---------------------------------------------------------------- GEMM 128x128, BK=64
// MODE 1: outF = resid + gmod[c]*(acc + bias[c])    (proj -> x1)
// MODE 5: outF = acc   (split-K partial, f32)
template<int MODE>
__global__ __launch_bounds__(256, 2) void gemm2_k(
    const u16* __restrict__ A, int lda,
    const u16* __restrict__ BTx, const u16* __restrict__ BTy, int ldb,
    const float* __restrict__ biasx, const float* __restrict__ biasy,
    const float* __restrict__ residx, const float* __restrict__ residy,
    const float* __restrict__ gmodx, const float* __restrict__ gmody,
    float* __restrict__ outF, int ldo,
    int K, int nb, int kparts)
{
    __shared__ u16 As[2][128*64];
    __shared__ u16 Bs[2][128*64];
    int nwg_base = 18 * nb;
    int nwg = nwg_base * kparts;
    int bid = blockIdx.x;
    int bid2 = (bid & 7) * (nwg >> 3) + (bid >> 3);
    int ks  = bid2 / nwg_base;
    int rem = bid2 % nwg_base;
    int bm = rem % 18, bn = rem / 18;
    int sel = (bm >= 16);
    int row0 = bm * 128, col0 = bn * 128;
    const u16* Bt = (sel ? BTy : BTx) + (size_t)ks * K;
    const u16* Ap = A + (size_t)ks * K;
    outF += (size_t)ks * NT_ * D_;

    int t = threadIdx.x, w = t >> 6, l = t & 63;
    int lrow = l & 15, lgrp = l >> 4;
    int wr = (w >> 1) * 64, wc = (w & 1) * 64;

    const char* Ab = (const char*)(Ap + (size_t)row0 * lda);
    const char* Bb = (const char*)(Bt + (size_t)col0 * ldb);
    u32 offA[4], offB[4], ldsoff[4];
    #pragma unroll
    for (int i = 0; i < 4; i++){
        int r = (i*4 + w)*8 + (l >> 3);
        int c = (l & 7) ^ (r & 7);
        offA[i]   = (u32)(r * lda + c * 8) * 2;
        offB[i]   = (u32)(r * ldb + c * 8) * 2;
        ldsoff[i] = (u32)((i*4 + w) * 1024);
    }

    #define STAGEG(bsel, kb) do{                                                  \
        _Pragma("unroll")                                                         \
        for (int i = 0; i < 4; i++)                                               \
            gll16(Ab + (offA[i] + (kb)), (char*)As + (bsel)*16384 + ldsoff[i]);   \
        _Pragma("unroll")                                                         \
        for (int i = 0; i < 4; i++)                                               \
            gll16(Bb + (offB[i] + (kb)), (char*)Bs + (bsel)*16384 + ldsoff[i]);   \
    } while(0)

    f32x4 acc[4][4];
    #pragma unroll
    for (int i = 0; i < 4; i++)
        #pragma unroll
        for (int j = 0; j < 4; j++) acc[i][j] = (f32x4){0.f,0.f,0.f,0.f};

    int nt = K >> 6;
    STAGEG(0, 0);

    for (int tt = 0; tt < nt; tt++){
        const u16* Ac = As[tt & 1];
        const u16* Bc = Bs[tt & 1];
        if (tt + 1 < nt){
            STAGEG((tt + 1) & 1, (u32)(tt + 1) * 128);
            asm volatile("s_waitcnt vmcnt(8)" ::: "memory");
        } else {
            asm volatile("s_waitcnt vmcnt(0)" ::: "memory");
        }
        __builtin_amdgcn_sched_barrier(0);
        __builtin_amdgcn_s_barrier();
        __builtin_amdgcn_sched_barrier(0);
        #pragma unroll
        for (int kk = 0; kk < 2; kk++){
            int pc = ((kk*4 + lgrp) ^ (lrow & 7)) * 8;
            short8 af[4], bf[4];
            #pragma unroll
            for (int mi = 0; mi < 4; mi++)
                af[mi] = *(const short8*)&Ac[(wr + mi*16 + lrow)*64 + pc];
            #pragma unroll
            for (int ni = 0; ni < 4; ni++)
                bf[ni] = *(const short8*)&Bc[(wc + ni*16 + lrow)*64 + pc];
            #pragma unroll
            for (int mi = 0; mi < 4; mi++)
                #pragma unroll
                for (int ni = 0; ni < 4; ni++)
                    acc[mi][ni] = __builtin_amdgcn_mfma_f32_16x16x32_bf16(
                                      af[mi], bf[ni], acc[mi][ni], 0, 0, 0);
        }
        asm volatile("s_waitcnt lgkmcnt(0)" ::: "memory");
        __builtin_amdgcn_sched_barrier(0);
        __builtin_amdgcn_s_barrier();
        __builtin_amdgcn_sched_barrier(0);
    }
    #undef STAGEG

    const float* biasp  = sel ? biasy  : biasx;
    const float* residp = sel ? residy : residx;
    const float* gmodp  = sel ? gmody  : gmodx;
    #pragma unroll
    for (int mi = 0; mi < 4; mi++){
        #pragma unroll
        for (int ni = 0; ni < 4; ni++){
            #pragma unroll
            for (int r = 0; r < 4; r++){
                int gr = row0 + wr + mi*16 + lgrp*4 + r;
                int gc = col0 + wc + ni*16 + lrow;
                float v = acc[mi][ni][r];
                size_t oi = (size_t)gr * ldo + gc;
                if (MODE == 1)      outF[oi] = residp[oi] + gmodp[gc] * (v + biasp[gc]);
                else if (MODE == 5) outF[oi] = v;
            }
        }
    }
}

// ---------------------------------------------------------------- split-K reduce (w3)
__global__ __launch_bounds__(256) void reduce_k(
    const float* __restrict__ p, const float* __restrict__ x1,
    const float* __restrict__ modx, const float* __restrict__ mody,
    float* __restrict__ dout)
{
    size_t i = ((size_t)blockIdx.x * 256 + threadIdx.x) * 4;
    float4 a = *(const float4*)&p[i];
    float4 b = *(const float4*)&p[(size_t)NT_ * D_ + i];
    float4 r = *(const float4*)&x1[i];
    int row = (int)(i / D_), col = (int)(i % D_);
    const float* g = (row < NX_ ? modx : mody) + 5*D_;
    float4 gv = *(const float4*)&g[col];
    float4 o;
    o.x = r.x + gv.x * (a.x + b.x);
    o.y = r.y + gv.y * (a.y + b.y);
    o.z = r.z + gv.z * (a.z + b.z);
    o.w = r.w + gv.w * (a.w + b.w);
    *(float4*)&dout[i] = o;
}

// ---------------------------------------------------------------- qkv postprocess
__global__ __launch_bounds__(256) void qkvpost_k(
    const u16* __restrict__ qkvraw, const int* __restrict__ positions,
    const float* __restrict__ qn_x, const float* __restrict__ kn_x,
    const float* __restrict__ qn_y, const float* __restrict__ kn_y,
    u16* __restrict__ Qg, u16* __restrict__ Kg, u16* __restrict__ Vg)
{
    int tok = blockIdx.x;
    int t = threadIdx.x, wave = t >> 6, lane = t & 63;
    bool isx = tok < NX_;
    float pos = isx ? (float)positions[tok] : 0.f;
    const float* qn = isx ? qn_x : qn_y;
    const float* kn = isx ? kn_x : kn_y;
    bool act = lane < 48;
    int d = lane * 2;
    #pragma unroll
    for (int hh = 0; hh < 4; hh++){
        int h = wave + hh * 4;
        const u16* base = qkvraw + (size_t)tok * (3*D_) + h * HD_;
        float qx=0.f,qy=0.f,kx=0.f,ky=0.f,vx=0.f,vy=0.f;
        if (act){
            u32 qw = *(const u32*)(base + d);
            u32 kw = *(const u32*)(base + D_ + d);
            u32 vw = *(const u32*)(base + 2*D_ + d);
            qx = bf2f((u16)qw); qy = bf2f((u16)(qw >> 16));
            kx = bf2f((u16)kw); ky = bf2f((u16)(kw >> 16));
            vx = bf2f((u16)vw); vy = bf2f((u16)(vw >> 16));
        }
        float sq = qx*qx + qy*qy, sk = kx*kx + ky*ky;
        for (int mask = 1; mask < 64; mask <<= 1){
            sq += __shfl_xor(sq, mask);
            sk += __shfl_xor(sk, mask);
        }
        float rq = rsqrtf(sq / (float)HD_ + EPS_);
        float rk = rsqrtf(sk / (float)HD_ + EPS_);
        if (act){
            qx *= rq * qn[d]; qy *= rq * qn[d+1];
            kx *= rk * kn[d]; ky *= rk * kn[d+1];
        }
        int pl = (lane < 36) ? lane + 12 : lane - 12;
        float qpx = __shfl(qx, pl), qpy = __shfl(qy, pl);
        float kpx = __shfl(kx, pl), kpy = __shfl(ky, pl);
        if (isx && lane >= 24 && act){
            bool aside = lane < 36;
            int i0 = aside ? (2*lane - 48) : (2*lane - 72);
            float ang0 = pos * __powf(10000.f, -(float)i0 / 24.f);
            float ang1 = pos * __powf(10000.f, -(float)(i0+1) / 24.f);
            float s0,c0,s1,c1;
            __sincosf(ang0, &s0, &c0);
            __sincosf(ang1, &s1, &c1);
            if (aside){
                qx = qx*c0 - qpx*s0;  qy = qy*c1 - qpy*s1;
                kx = kx*c0 - kpx*s0;  ky = ky*c1 - kpy*s1;
            } else {
                qx = qx*c0 + qpx*s0;  qy = qy*c1 + qpy*s1;
                kx = kx*c0 + kpx*s0;  ky = ky*c1 + kpy*s1;
            }
        }
        size_t o96  = ((size_t)h * NT_ + tok) * 96;
        size_t o128 = ((size_t)h * NT_ + tok) * 128;
        if (act){
            Qg[o96 + d] = f2bf(qx);  Qg[o96 + d + 1] = f2bf(qy);
            Kg[o128 + d] = f2bf(kx); Kg[o128 + d + 1] = f2bf(ky);
            Vg[o96 + d] = f2bf(vx);  Vg[o96 + d + 1] = f2bf(vy);
        } else {
            int dp = 96 + (lane - 48) * 2;     // zero K pad 96..127
            Kg[o128 + dp] = 0; Kg[o128 + dp + 1] = 0;
        }
    }
}

// ---------------------------------------------------------------- V transpose
__global__ __launch_bounds__(256) void vtrans_k(
    const u16* __restrict__ Vg, u16* __restrict__ Vtg)
{
    int h = blockIdx.y, t0 = blockIdx.x * 64;
    __shared__ u16 tile[64][104];
    int t = threadIdx.x;
    #pragma unroll
    for (int i = 0; i < 3; i++){
        int idx = i*256 + t;
        int tok = idx / 12, c = idx % 12;
        uint4 v = *(const uint4*)&Vg[((size_t)h*NT_ + t0 + tok)*96 + c*8];
        *(uint4*)&tile[tok][c*8] = v;
    }
    __syncthreads();
    #pragma unroll
    for (int i = 0; i < 3; i++){
        int idx = i*256 + t;
        int d = idx >> 3, tc = idx & 7;
        u16 vv[8];
        #pragma unroll
        for (int j = 0; j < 8; j++) vv[j] = tile[tc*8 + j][d];
        *(uint4*)&Vtg[((size_t)h*128 + d)*NT_ + t0 + tc*8] = *(uint4*)vv;
    }
    {
        int row = 96 + (t >> 3), tc = t & 7;
        u16 val = (row == 96) ? (u16)0x3F80 : (u16)0;
        u16 vv[8];
        #pragma unroll
        for (int j = 0; j < 8; j++) vv[j] = val;
        *(uint4*)&Vtg[((size_t)h*128 + row)*NT_ + t0 + tc*8] = *(uint4*)vv;
    }
}

// ---------------------------------------------------------------- flash attention (split-KV x4)
// O-partials in bf16 (pbO), row-sums l in f32 (pbL, exact). 9 KV tiles/block.
__global__ __launch_bounds__(256, 4) void attn_k(
    const u16* __restrict__ Qg, const u16* __restrict__ Kg,
    const u16* __restrict__ Vtg, u16* __restrict__ pbO, float* __restrict__ pbL)
{
    int bid = blockIdx.x;
    int kvh = bid / 576;                       // 0..3
    int bb  = bid % 576;
    int bid2 = (bb & 7) * 72 + (bb >> 3);      // same-XCD for all quarters
    int h = bid2 / 36;
    int q0 = (bid2 % 36) * 64;
    __shared__ u16 Ks[64*128];
    __shared__ u16 Vs[112*64];
    __shared__ u16 Ps[4][16*72];
    int t = threadIdx.x, wave = t >> 6, lane = t & 63;
    int lrow = lane & 15, lgrp = lane >> 4;
    const float C1 = (float)(0.10206207261596577 * 1.4426950408889634);
    const float C2 = (float)(-10.0 * 1.4426950408889634);

    const u16* qbase = Qg + ((size_t)h * NT_ + q0 + wave*16 + lrow) * 96;
    short8 qf[3];
    #pragma unroll
    for (int c = 0; c < 3; c++) qf[c] = *(const short8*)(qbase + c*32 + lgrp*8);

    const u16* Kbh = Kg  + (size_t)h * NT_ * 128;
    const u16* Vbh = Vtg + (size_t)h * 128 * NT_;

    int krow[4], kc_[4], vrow[4], vc_[4];
    #pragma unroll
    for (int i = 0; i < 4; i++){
        int g = wave*4 + i;
        krow[i] = g*4 + (lane >> 4);
        kc_[i]  = (lane & 15) ^ (krow[i] & 7);
        vrow[i] = g*8 + (lane >> 3);
        vc_[i]  = (lane & 7) ^ (vrow[i] & 7);
    }

    f32x4 oacc[7];
    #pragma unroll
    for (int n = 0; n < 7; n++) oacc[n] = (f32x4){0.f,0.f,0.f,0.f};

    int kt0 = kvh * 9;
    for (int kt = kt0; kt < kt0 + 9; kt++){
        __syncthreads();
        #pragma unroll
        for (int i = 0; i < 4; i++)
            gll16(Kbh + ((size_t)(kt*64 + krow[i]))*128 + kc_[i]*8,
                  &Ks[(wave*4 + i)*512 + lane*8]);
        #pragma unroll
        for (int i = 0; i < 4; i++){
            int g = wave*4 + i;
            if (g < 14)
                gll16(Vbh + (size_t)vrow[i]*NT_ + kt*64 + vc_[i]*8,
                      &Vs[g*512 + lane*8]);
        }
        __syncthreads();

        f32x4 s[4];
        #pragma unroll
        for (int nt = 0; nt < 4; nt++){
            s[nt] = (f32x4){0.f,0.f,0.f,0.f};
            #pragma unroll
            for (int c = 0; c < 3; c++){
                int pc = ((c*4 + lgrp) ^ (lrow & 7)) * 8;
                short8 kf = *(const short8*)&Ks[(nt*16 + lrow)*128 + pc];
                s[nt] = __builtin_amdgcn_mfma_f32_16x16x32_bf16(kf, qf[c], s[nt], 0,0,0);
            }
        }
        // P = exp2(s*C1 + C2) -> bf16 via packed RNE convert (v_cvt_pk_bf16_f32)
        #pragma unroll
        for (int nt = 0; nt < 4; nt++){
            float e0 = exp2f(fmaf(s[nt][0], C1, C2));
            float e1 = exp2f(fmaf(s[nt][1], C1, C2));
            float e2 = exp2f(fmaf(s[nt][2], C1, C2));
            float e3 = exp2f(fmaf(s[nt][3], C1, C2));
            float2 f01; f01.x = e0; f01.y = e1;
            float2 f23; f23.x = e2; f23.y = e3;
            __hip_bfloat162 h0 = __float22bfloat162_rn(f01);
            __hip_bfloat162 h1 = __float22bfloat162_rn(f23);
            uint2 pk;
            pk.x = *reinterpret_cast<u32*>(&h0);
            pk.y = *reinterpret_cast<u32*>(&h1);
            *(uint2*)&Ps[wave][lrow*72 + nt*16 + lgrp*4] = pk;
        }
        #pragma unroll
        for (int kc2 = 0; kc2 < 2; kc2++){
            short8 pf = *(const short8*)&Ps[wave][lrow*72 + kc2*32 + lgrp*8];
            #pragma unroll
            for (int n = 0; n < 7; n++){
                int pc = ((kc2*4 + lgrp) ^ (lrow & 7)) * 8;
                short8 vf = *(const short8*)&Vs[(n*16 + lrow)*64 + pc];
                oacc[n] = __builtin_amdgcn_mfma_f32_16x16x32_bf16(pf, vf, oacc[n], 0,0,0);
            }
        }
    }

    // O partials -> bf16 [64][96]; l -> f32 [64]
    u16* po = pbO + ((size_t)(bid2*4 + kvh)) * (64*96);
    #pragma unroll
    for (int n = 0; n < 6; n++){
        #pragma unroll
        for (int r = 0; r < 4; r++){
            int row = wave*16 + lgrp*4 + r;
            po[(size_t)row * 96 + n*16 + lrow] = f2bf(oacc[n][r]);
        }
    }
    if (lrow == 0){
        float* pl = pbL + ((size_t)(bid2*4 + kvh)) * 64;
        #pragma unroll
        for (int r = 0; r < 4; r++)
            pl[wave*16 + lgrp*4 + r] = oacc[6][r];
    }
}

// combine quarters: Og = (o0+o1+o2+o3)/(l0+l1+l2+l3)   (vectorized u16x8)
__global__ __launch_bounds__(256) void attncomb_k(
    const u16* __restrict__ pbO, const float* __restrict__ pbL,
    u16* __restrict__ Og)
{
    int cid = blockIdx.x;              // 0..575 == bid2
    int h = cid / 36, q0 = (cid % 36) * 64;
    const u16* o0 = pbO + ((size_t)(cid*4 + 0)) * (64*96);
    const u16* o1 = pbO + ((size_t)(cid*4 + 1)) * (64*96);
    const u16* o2 = pbO + ((size_t)(cid*4 + 2)) * (64*96);
    const u16* o3 = pbO + ((size_t)(cid*4 + 3)) * (64*96);
    const float* l0 = pbL + ((size_t)(cid*4 + 0)) * 64;
    const float* l1 = pbL + ((size_t)(cid*4 + 1)) * 64;
    const float* l2 = pbL + ((size_t)(cid*4 + 2)) * 64;
    const float* l3 = pbL + ((size_t)(cid*4 + 3)) * 64;
    for (int e = threadIdx.x; e < 64*12; e += 256){
        int row = e / 12, ch = e % 12;
        float inv = 1.f / (l0[row] + l1[row] + l2[row] + l3[row]);
        short8 a = *(const short8*)&o0[(size_t)row*96 + ch*8];
        short8 b = *(const short8*)&o1[(size_t)row*96 + ch*8];
        short8 c = *(const short8*)&o2[(size_t)row*96 + ch*8];
        short8 d = *(const short8*)&o3[(size_t)row*96 + ch*8];
        u16 ov[8];
        #pragma unroll
        for (int j = 0; j < 8; j++)
            ov[j] = f2bf((bf2f((u16)a[j]) + bf2f((u16)b[j])
                        + bf2f((u16)c[j]) + bf2f((u16)d[j])) * inv);
        *(uint4*)&Og[(size_t)(q0 + row) * D_ + h*HD_ + ch*8] = *(uint4*)ov;
    }
}

// ---------------------------------------------------------------- launcher
extern "C" void kernel_launch(void* const* d_in, const int* in_sizes, int n_in,
                              void* d_out, int out_size, void* d_ws, size_t ws_size,
                              hipStream_t stream)
{
    const float* x        = (const float*)d_in[0];
    const float* y        = (const float*)d_in[1];
    const float* tt       = (const float*)d_in[2];
    const int*   pos      = (const int*)  d_in[3];
    const float* w_mod_x  = (const float*)d_in[4];
    const float* b_mod_x  = (const float*)d_in[5];
    const float* w_mod_y  = (const float*)d_in[6];
    const float* b_mod_y  = (const float*)d_in[7];
    const float* w_qkv_x  = (const float*)d_in[8];
    const float* b_qkv_x  = (const float*)d_in[9];
    const float* w_qkv_y  = (const float*)d_in[10];
    const float* b_qkv_y  = (const float*)d_in[11];
    const float* qn_x     = (const float*)d_in[12];
    const float* kn_x     = (const float*)d_in[13];
    const float* qn_y     = (const float*)d_in[14];
    const float* kn_y     = (const float*)d_in[15];
    const float* w_proj_x = (const float*)d_in[16];
    const float* b_proj_x = (const float*)d_in[17];
    const float* w_proj_y = (const float*)d_in[18];
    const float* b_proj_y = (const float*)d_in[19];
    const float* w1_x     = (const float*)d_in[20];
    const float* w2_x     = (const float*)d_in[21];
    const float* w3_x     = (const float*)d_in[22];
    const float* w1_y     = (const float*)d_in[23];
    const float* w2_y     = (const float*)d_in[24];
    const float* w3_y     = (const float*)d_in[25];
    float* dout = (float*)d_out;

    char* ws = (char*)d_ws;
    size_t off = 0;
    float* modx   = (float*)(ws + off); off += (size_t)(6*D_) * 4;
    float* mody   = (float*)(ws + off); off += (size_t)(6*D_) * 4;
    u16*   a      = (u16*)  (ws + off); off += (size_t)NT_ * D_ * 2;        // 7.08 MB
    u16*   arena  = (u16*)  (ws + off); off += (size_t)2 * D_ * FF_ * 2;    // 37.75 MB
    u16*   r1     = (u16*)  (ws + off); off += (size_t)NT_ * FF_ * 2;       // 28.31 MB
    u16*   r2     = (u16*)  (ws + off); off += ((size_t)3*96 + 128) * H_ * NT_ * 2; // 30.72 MB
    float* x1     = (float*)(ws + off); off += (size_t)NT_ * D_ * 4;        // 14.16 MB
    u16*   Vtg    = (u16*)  (ws + off); off += (size_t)H_ * 128 * NT_ * 2;  // 9.44 MB

    // region overlays (liveness-checked):
    float* pmod   = (float*)arena;                        // modvec partials
    u16*   attnO  = arena;                                // attn O partials 28.3 MB
    float* attnL  = (float*)(arena + (size_t)2304*64*96); // attn l partials 0.59 MB
    u16*   qkvraw = r1;
    u16*   hs     = r1;
    float* p0     = (float*)r1;
    u16*   Qb     = r2;
    u16*   Kb     = r2 + (size_t)H_ * NT_ * 96;            // padded [tok][128]
    u16*   Vb     = r2 + (size_t)H_ * NT_ * (96 + 128);
    u16*   Ob     = r2 + (size_t)H_ * NT_ * (2*96 + 128);
    u16*   hb     = r2;

    const size_t qkvW  = (size_t)D_ * (3*D_);
    const size_t projW = (size_t)D_ * D_;
    const size_t ffW   = (size_t)D_ * FF_;

    // 1) modulation vectors (split-K x16) + LN/mod1
    modvec2_k<<<dim3(72, 16), 256, 0, stream>>>(tt, w_mod_x, w_mod_y, pmod);
    reducemod_k<<<72, 256, 0, stream>>>(pmod, b_mod_x, b_mod_y, modx, mody);
    lnmod_k<<<NT_, 256, 0, stream>>>(x, y, modx, mody, 0, a);
    // 2) qkv (256^2)
    transpose_k<<<dim3(48*144, 2), 256, 0, stream>>>(w_qkv_x, w_qkv_y, arena, arena + qkvW, D_, 3*D_);
    gemm3_k<0><<<9*18, 512, 0, stream>>>(a, arena, arena + qkvW, b_qkv_x, b_qkv_y,
        nullptr, qkvraw, 3*D_, D_, 9, 18);
    // 3) RMS + RoPE + reshape (K padded 128); V transpose
    qkvpost_k<<<NT_, 256, 0, stream>>>(qkvraw, pos, qn_x, kn_x, qn_y, kn_y, Qb, Kb, Vb);
    vtrans_k<<<dim3(36, 16), 256, 0, stream>>>(Vb, Vtg);
    // 4) attention split-KV x4 -> bf16 O partials + f32 l, combine -> Ob
    attn_k<<<2304, 256, 0, stream>>>(Qb, Kb, Vtg, attnO, attnL);
    attncomb_k<<<576, 256, 0, stream>>>(attnO, attnL, Ob);
    // 5) proj + residual -> x1
    transpose_k<<<dim3(48*48, 2), 256, 0, stream>>>(w_proj_x, w_proj_y, arena, arena + projW, D_, D_);
    gemm2_k<1><<<18*12, 256, 0, stream>>>(Ob, D_, arena, arena + projW, D_,
        b_proj_x, b_proj_y, x, y - (size_t)NX_*D_, modx + 2*D_, mody + 2*D_,
        x1, D_, D_, 12, 1);
    // 6) LN/mod2
    lnmod_k<<<NT_, 256, 0, stream>>>(x1, x1 + (size_t)NX_*D_, modx, mody, 3*D_, a);
    // 7) ffn w1 -> silu -> hs (256^2)
    transpose_k<<<dim3(48*192, 2), 256, 0, stream>>>(w1_x, w1_y, arena, arena + ffW, D_, FF_);
    gemm3_k<2><<<9*24, 512, 0, stream>>>(a, arena, arena + ffW, nullptr, nullptr,
        nullptr, hs, FF_, D_, 9, 24);
    // 8) ffn w2 * hs -> hb (256^2)
    transpose_k<<<dim3(48*192, 2), 256, 0, stream>>>(w2_x, w2_y, arena, arena + ffW, D_, FF_);
    gemm3_k<3><<<9*24, 512, 0, stream>>>(a, arena, arena + ffW, nullptr, nullptr,
        hs, hb, FF_, D_, 9, 24);
    // 9) w3 split-K x2 -> partials, fused reduce -> d_out
    transpose_k<<<dim3(192*48, 2), 256, 0, stream>>>(w3_x, w3_y, arena, arena + ffW, FF_, D_);
    gemm2_k<5><<<18*12*2, 256, 0, stream>>>(hb, FF_, arena, arena + ffW, FF_,
        nullptr, nullptr, nullptr, nullptr, nullptr, nullptr,
        p0, D_, 3072, 12, 2);
    reduce_k<<<(NT_*D_/4)/256, 256, 0, stream>>>(p0, x1, modx, mody, dout);
    (void)in_sizes; (void)n_in; (void)out_size; (void)ws_size;
}

// Round 21
// 476.213 us; speedup vs baseline: 1.0057x; 1.0057x over previous
//
#include <hip/hip_runtime.h>
#include <hip/hip_bf16.h>

#define D_  1536
#define H_  16
#define HD_ 96
#define NX_ 2048
#define NY_ 256
#define NT_ 2304
#define FF_ 6144
#define EPS_ 1e-6f

typedef unsigned short u16;
typedef unsigned int   u32;
typedef short short8 __attribute__((ext_vector_type(8)));
typedef float f32x4  __attribute__((ext_vector_type(4)));
typedef unsigned short u16x4 __attribute__((ext_vector_type(4)));

__device__ __forceinline__ u16 f2bf(float f){
    u32 u = __float_as_uint(f);
    return (u16)((u + 0x7fffu + ((u >> 16) & 1u)) >> 16);   // RNE
}
__device__ __forceinline__ float bf2f(u16 h){ return __uint_as_float(((u32)h) << 16); }

__device__ __forceinline__ void gll16(const void* g, void* l){
    __builtin_amdgcn_global_load_lds(
        (const __attribute__((address_space(1))) unsigned int*)g,
        (__attribute__((address_space(3))) unsigned int*)l, 16, 0, 0);
}

// ---------------------------------------------------------------- weight transpose
__global__ __launch_bounds__(256) void transpose_k(
    const float* __restrict__ Wx, const float* __restrict__ Wy,
    u16* __restrict__ Ox, u16* __restrict__ Oy, int K, int N)
{
    const float* W = blockIdx.y ? Wy : Wx;
    u16* O = blockIdx.y ? Oy : Ox;
    int tn_cnt = N >> 5;
    int tk = blockIdx.x / tn_cnt, tn = blockIdx.x % tn_cnt;
    __shared__ float tile[32][33];
    int t = threadIdx.x;
    {
        int k = t >> 3, n4 = (t & 7) * 4;
        float4 v = *(const float4*)&W[(size_t)(tk*32 + k) * N + tn*32 + n4];
        tile[k][n4+0] = v.x; tile[k][n4+1] = v.y;
        tile[k][n4+2] = v.z; tile[k][n4+3] = v.w;
    }
    __syncthreads();
    {
        int n = t >> 3, k4 = (t & 7) * 4;
        u16x4 r;
        #pragma unroll
        for (int i = 0; i < 4; i++) r[i] = f2bf(tile[k4+i][n]);
        *(u16x4*)&O[(size_t)(tn*32 + n) * K + tk*32 + k4] = r;
    }
}

// ---------------------------------------------------------------- mod GEMV (split-K x16)
__global__ __launch_bounds__(256) void modvec2_k(
    const float* __restrict__ t_in,
    const float* __restrict__ w_mod_x, const float* __restrict__ w_mod_y,
    float* __restrict__ pbuf)
{
    int part = blockIdx.y;
    int j = blockIdx.x * 256 + threadIdx.x;
    __shared__ float st[96];
    int k0 = part * 96;
    if (threadIdx.x < 96){
        float v = t_in[k0 + threadIdx.x];
        st[threadIdx.x] = v / (1.f + __expf(-v));
    }
    __syncthreads();
    const float* W; int col;
    if (j < 6*D_){ W = w_mod_x; col = j; }
    else         { W = w_mod_y; col = j - 6*D_; }
    const float* wp = W + (size_t)k0 * (6*D_) + col;
    float acc = 0.f;
    #pragma unroll 8
    for (int k = 0; k < 96; k++)
        acc += st[k] * wp[(size_t)k * (6*D_)];
    pbuf[(size_t)part * 18432 + j] = acc;
}

__global__ __launch_bounds__(256) void reducemod_k(
    const float* __restrict__ pbuf,
    const float* __restrict__ b_mod_x, const float* __restrict__ b_mod_y,
    float* __restrict__ modx, float* __restrict__ mody)
{
    int j = blockIdx.x * 256 + threadIdx.x;
    float acc = (j < 6*D_) ? b_mod_x[j] : b_mod_y[j - 6*D_];
    #pragma unroll
    for (int p = 0; p < 16; p++)
        acc += pbuf[(size_t)p * 18432 + j];
    if (j < 6*D_) modx[j] = acc;
    else          mody[j - 6*D_] = acc;
}

// ---------------------------------------------------------------- LN + modulate -> bf16
__global__ __launch_bounds__(256) void lnmod_k(
    const float* __restrict__ inx, const float* __restrict__ iny,
    const float* __restrict__ modx, const float* __restrict__ mody,
    int shoff, u16* __restrict__ out)
{
    int row = blockIdx.x, t = threadIdx.x;
    const float* in; const float* mod;
    if (row < NX_){ in = inx + (size_t)row * D_;        mod = modx; }
    else          { in = iny + (size_t)(row-NX_) * D_;  mod = mody; }
    const float* sh = mod + shoff;
    const float* sc = mod + shoff + D_;
    float vals[6]; float s = 0.f, ss = 0.f;
    #pragma unroll
    for (int j = 0; j < 6; j++){
        float v = in[t + j*256];
        vals[j] = v; s += v; ss += v*v;
    }
    for (int mask = 1; mask < 64; mask <<= 1){
        s  += __shfl_xor(s,  mask);
        ss += __shfl_xor(ss, mask);
    }
    __shared__ float red[2][4];
    int wave = t >> 6, lane = t & 63;
    if (lane == 0){ red[0][wave] = s; red[1][wave] = ss; }
    __syncthreads();
    s  = red[0][0] + red[0][1] + red[0][2] + red[0][3];
    ss = red[1][0] + red[1][1] + red[1][2] + red[1][3];
    float mean = s * (1.f / D_);
    float var  = ss * (1.f / D_) - mean * mean;
    float inv  = rsqrtf(var + EPS_);
    #pragma unroll
    for (int j = 0; j < 6; j++){
        int c = t + j*256;
        float z = (vals[j] - mean) * inv;
        z = z * (1.f + sc[c]) + sh[c];
        out[(size_t)row * D_ + c] = f2bf(z);
    }
}

// ---------------------------------------------------------------- GEMM 256x256, BK=64
template<int MODE>
__global__ __launch_bounds__(512, 2) void gemm3_k(
    const u16* __restrict__ A,
    const u16* __restrict__ BTx, const u16* __restrict__ BTy,
    const float* __restrict__ biasx, const float* __restrict__ biasy,
    const u16* __restrict__ hmul,
    u16* __restrict__ outB, int ldo,
    int K, int mb, int nb)
{
    __shared__ u16 As[2][256*64];
    __shared__ u16 Bs[2][256*64];
    int nwg = mb * nb;
    int bid = blockIdx.x;
    int q = nwg >> 3, r = nwg & 7, xcd = bid & 7;    // bijective XCD swizzle (m204)
    int wgid = (xcd < r ? xcd*(q+1) : r*(q+1) + (xcd - r)*q) + (bid >> 3);
    int bm = wgid % mb, bn = wgid / mb;
    int sel = (bm == mb - 1);
    int row0 = bm * 256, col0 = bn * 256;
    const u16* Bt = sel ? BTy : BTx;

    int t = threadIdx.x, wid = t >> 6, lane = t & 63;
    int lrow = lane & 15, lgrp = lane >> 4;
    int wr = (wid >> 2) * 128, wc = (wid & 3) * 64;

    const char* Ab = (const char*)(A  + (size_t)row0 * K);
    const char* Bb = (const char*)(Bt + (size_t)col0 * K);
    u32 offG[4], offL[4];
    #pragma unroll
    for (int i = 0; i < 4; i++){
        int rr = i*64 + (t >> 3);
        int cc = (t & 7) ^ (rr & 7);
        offG[i] = (u32)(rr * K + cc * 8) * 2;
        offL[i] = (u32)(i*8192 + t*16);
    }

    #define STAGEG(bsel, kb) do{                                                  \
        _Pragma("unroll")                                                         \
        for (int i = 0; i < 4; i++)                                               \
            gll16(Ab + (offG[i] + (kb)), (char*)As[bsel] + offL[i]);              \
        _Pragma("unroll")                                                         \
        for (int i = 0; i < 4; i++)                                               \
            gll16(Bb + (offG[i] + (kb)), (char*)Bs[bsel] + offL[i]);              \
    } while(0)

    f32x4 acc[8][4];
    #pragma unroll
    for (int i = 0; i < 8; i++)
        #pragma unroll
        for (int j = 0; j < 4; j++) acc[i][j] = (f32x4){0.f,0.f,0.f,0.f};

    int nt = K >> 6;
    STAGEG(0, 0);

    for (int tt = 0; tt < nt; tt++){
        const u16* Ac = As[tt & 1];
        const u16* Bc = Bs[tt & 1];
        if (tt + 1 < nt){
            STAGEG((tt + 1) & 1, (u32)(tt + 1) * 128);
            asm volatile("s_waitcnt vmcnt(8)" ::: "memory");
        } else {
            asm volatile("s_waitcnt vmcnt(0)" ::: "memory");
        }
        __builtin_amdgcn_sched_barrier(0);
        __builtin_amdgcn_s_barrier();
        __builtin_amdgcn_sched_barrier(0);
        #pragma unroll
        for (int kk = 0; kk < 2; kk++){
            int pc = ((kk*4 + lgrp) ^ (lrow & 7)) * 8;
            short8 bf[4];
            #pragma unroll
            for (int ni = 0; ni < 4; ni++)
                bf[ni] = *(const short8*)&Bc[(wc + ni*16 + lrow)*64 + pc];
            #pragma unroll
            for (int mi = 0; mi < 8; mi++){
                short8 af = *(const short8*)&Ac[(wr + mi*16 + lrow)*64 + pc];
                #pragma unroll
                for (int ni = 0; ni < 4; ni++)
                    acc[mi][ni] = __builtin_amdgcn_mfma_f32_16x16x32_bf16(
                                      af, bf[ni], acc[mi][ni], 0, 0, 0);
            }
        }
        asm volatile("s_waitcnt lgkmcnt(0)" ::: "memory");
        __builtin_amdgcn_sched_barrier(0);
        __builtin_amdgcn_s_barrier();
        __builtin_amdgcn_sched_barrier(0);
    }
    #undef STAGEG

    const float* biasp = sel ? biasy : biasx;
    #pragma unroll
    for (int mi = 0; mi < 8; mi++){
        #pragma unroll
        for (int ni = 0; ni < 4; ni++){
            #pragma unroll
            for (int rr = 0; rr < 4; rr++){
                int gr = row0 + wr + mi*16 + lgrp*4 + rr;
                int gc = col0 + wc + ni*16 + lrow;
                float v = acc[mi][ni][rr];
                size_t oi = (size_t)gr * ldo + gc;
                if (MODE == 0)      outB[oi] = f2bf(v + biasp[gc]);
                else if (MODE == 2) outB[oi] = f2bf(v / (1.f + __expf(-v)));
                else if (MODE == 3) outB[oi] = f2bf(bf2f(hmul[oi]) * v);
            }
        }
    }
}

// ---------------------------------------------------------------- GEMM 128x128, BK=64
// MODE 1: outF = resid + gmod[c]*(acc + bias[c])    (proj -> x1)
// MODE 5: outF = acc   (split-K partial, f32)
template<int MODE>
__global__ __launch_bounds__(256, 2) void gemm2_k(
    const u16* __restrict__ A, int lda,
    const u16* __restrict__ BTx, const u16* __restrict__ BTy, int ldb,
    const float* __restrict__ biasx, const float* __restrict__ biasy,
    const float* __restrict__ residx, const float* __restrict__ residy,
    const float* __restrict__ gmodx, const float* __restrict__ gmody,
    float* __restrict__ outF, int ldo,
    int K, int nb, int kparts)
{
    __shared__ u16 As[2][128*64];
    __shared__ u16 Bs[2][128*64];
    int nwg_base = 18 * nb;
    int nwg = nwg_base * kparts;
    int bid = blockIdx.x;
    int bid2 = (bid & 7) * (nwg >> 3) + (bid >> 3);
    int ks  = bid2 / nwg_base;
    int rem = bid2 % nwg_base;
    int bm = rem % 18, bn = rem / 18;
    int sel = (bm >= 16);
    int row0 = bm * 128, col0 = bn * 128;
    const u16* Bt = (sel ? BTy : BTx) + (size_t)ks * K;
    const u16* Ap = A + (size_t)ks * K;
    outF += (size_t)ks * NT_ * D_;

    int t = threadIdx.x, w = t >> 6, l = t & 63;
    int lrow = l & 15, lgrp = l >> 4;
    int wr = (w >> 1) * 64, wc = (w & 1) * 64;

    const char* Ab = (const char*)(Ap + (size_t)row0 * lda);
    const char* Bb = (const char*)(Bt + (size_t)col0 * ldb);
    u32 offA[4], offB[4], ldsoff[4];
    #pragma unroll
    for (int i = 0; i < 4; i++){
        int r = (i*4 + w)*8 + (l >> 3);
        int c = (l & 7) ^ (r & 7);
        offA[i]   = (u32)(r * lda + c * 8) * 2;
        offB[i]   = (u32)(r * ldb + c * 8) * 2;
        ldsoff[i] = (u32)((i*4 + w) * 1024);
    }

    #define STAGEG(bsel, kb) do{                                                  \
        _Pragma("unroll")                                                         \
        for (int i = 0; i < 4; i++)                                               \
            gll16(Ab + (offA[i] + (kb)), (char*)As + (bsel)*16384 + ldsoff[i]);   \
        _Pragma("unroll")                                                         \
        for (int i = 0; i < 4; i++)                                               \
            gll16(Bb + (offB[i] + (kb)), (char*)Bs + (bsel)*16384 + ldsoff[i]);   \
    } while(0)

    f32x4 acc[4][4];
    #pragma unroll
    for (int i = 0; i < 4; i++)
        #pragma unroll
        for (int j = 0; j < 4; j++) acc[i][j] = (f32x4){0.f,0.f,0.f,0.f};

    int nt = K >> 6;
    STAGEG(0, 0);

    for (int tt = 0; tt < nt; tt++){
        const u16* Ac = As[tt & 1];
        const u16* Bc = Bs[tt & 1];
        if (tt + 1 < nt){
            STAGEG((tt + 1) & 1, (u32)(tt + 1) * 128);
            asm volatile("s_waitcnt vmcnt(8)" ::: "memory");
        } else {
            asm volatile("s_waitcnt vmcnt(0)" ::: "memory");
        }
        __builtin_amdgcn_sched_barrier(0);
        __builtin_amdgcn_s_barrier();
        __builtin_amdgcn_sched_barrier(0);
        #pragma unroll
        for (int kk = 0; kk < 2; kk++){
            int pc = ((kk*4 + lgrp) ^ (lrow & 7)) * 8;
            short8 af[4], bf[4];
            #pragma unroll
            for (int mi = 0; mi < 4; mi++)
                af[mi] = *(const short8*)&Ac[(wr + mi*16 + lrow)*64 + pc];
            #pragma unroll
            for (int ni = 0; ni < 4; ni++)
                bf[ni] = *(const short8*)&Bc[(wc + ni*16 + lrow)*64 + pc];
            #pragma unroll
            for (int mi = 0; mi < 4; mi++)
                #pragma unroll
                for (int ni = 0; ni < 4; ni++)
                    acc[mi][ni] = __builtin_amdgcn_mfma_f32_16x16x32_bf16(
                                      af[mi], bf[ni], acc[mi][ni], 0, 0, 0);
        }
        asm volatile("s_waitcnt lgkmcnt(0)" ::: "memory");
        __builtin_amdgcn_sched_barrier(0);
        __builtin_amdgcn_s_barrier();
        __builtin_amdgcn_sched_barrier(0);
    }
    #undef STAGEG

    const float* biasp  = sel ? biasy  : biasx;
    const float* residp = sel ? residy : residx;
    const float* gmodp  = sel ? gmody  : gmodx;
    #pragma unroll
    for (int mi = 0; mi < 4; mi++){
        #pragma unroll
        for (int ni = 0; ni < 4; ni++){
            #pragma unroll
            for (int r = 0; r < 4; r++){
                int gr = row0 + wr + mi*16 + lgrp*4 + r;
                int gc = col0 + wc + ni*16 + lrow;
                float v = acc[mi][ni][r];
                size_t oi = (size_t)gr * ldo + gc;
                if (MODE == 1)      outF[oi] = residp[oi] + gmodp[gc] * (v + biasp[gc]);
                else if (MODE == 5) outF[oi] = v;
            }
        }
    }
}

// ---------------------------------------------------------------- split-K reduce (w3)
__global__ __launch_bounds__(256) void reduce_k(
    const float* __restrict__ p, const float* __restrict__ x1,
    const float* __restrict__ modx, const float* __restrict__ mody,
    float* __restrict__ dout)
{
    size_t i = ((size_t)blockIdx.x * 256 + threadIdx.x) * 4;
    float4 a = *(const float4*)&p[i];
    float4 b = *(const float4*)&p[(size_t)NT_ * D_ + i];
    float4 r = *(const float4*)&x1[i];
    int row = (int)(i / D_), col = (int)(i % D_);
    const float* g = (row < NX_ ? modx : mody) + 5*D_;
    float4 gv = *(const float4*)&g[col];
    float4 o;
    o.x = r.x + gv.x * (a.x + b.x);
    o.y = r.y + gv.y * (a.y + b.y);
    o.z = r.z + gv.z * (a.z + b.z);
    o.w = r.w + gv.w * (a.w + b.w);
    *(float4*)&dout[i] = o;
}

// ---------------------------------------------------------------- qkv postprocess
__global__ __launch_bounds__(256) void qkvpost_k(
    const u16* __restrict__ qkvraw, const int* __restrict__ positions,
    const float* __restrict__ qn_x, const float* __restrict__ kn_x,
    const float* __restrict__ qn_y, const float* __restrict__ kn_y,
    u16* __restrict__ Qg, u16* __restrict__ Kg, u16* __restrict__ Vg)
{
    int tok = blockIdx.x;
    int t = threadIdx.x, wave = t >> 6, lane = t & 63;
    bool isx = tok < NX_;
    float pos = isx ? (float)positions[tok] : 0.f;
    const float* qn = isx ? qn_x : qn_y;
    const float* kn = isx ? kn_x : kn_y;
    bool act = lane < 48;
    int d = lane * 2;
    #pragma unroll
    for (int hh = 0; hh < 4; hh++){
        int h = wave + hh * 4;
        const u16* base = qkvraw + (size_t)tok * (3*D_) + h * HD_;
        float qx=0.f,qy=0.f,kx=0.f,ky=0.f,vx=0.f,vy=0.f;
        if (act){
            u32 qw = *(const u32*)(base + d);
            u32 kw = *(const u32*)(base + D_ + d);
            u32 vw = *(const u32*)(base + 2*D_ + d);
            qx = bf2f((u16)qw); qy = bf2f((u16)(qw >> 16));
            kx = bf2f((u16)kw); ky = bf2f((u16)(kw >> 16));
            vx = bf2f((u16)vw); vy = bf2f((u16)(vw >> 16));
        }
        float sq = qx*qx + qy*qy, sk = kx*kx + ky*ky;
        for (int mask = 1; mask < 64; mask <<= 1){
            sq += __shfl_xor(sq, mask);
            sk += __shfl_xor(sk, mask);
        }
        float rq = rsqrtf(sq / (float)HD_ + EPS_);
        float rk = rsqrtf(sk / (float)HD_ + EPS_);
        if (act){
            qx *= rq * qn[d]; qy *= rq * qn[d+1];
            kx *= rk * kn[d]; ky *= rk * kn[d+1];
        }
        int pl = (lane < 36) ? lane + 12 : lane - 12;
        float qpx = __shfl(qx, pl), qpy = __shfl(qy, pl);
        float kpx = __shfl(kx, pl), kpy = __shfl(ky, pl);
        if (isx && lane >= 24 && act){
            bool aside = lane < 36;
            int i0 = aside ? (2*lane - 48) : (2*lane - 72);
            float ang0 = pos * __powf(10000.f, -(float)i0 / 24.f);
            float ang1 = pos * __powf(10000.f, -(float)(i0+1) / 24.f);
            float s0,c0,s1,c1;
            __sincosf(ang0, &s0, &c0);
            __sincosf(ang1, &s1, &c1);
            if (aside){
                qx = qx*c0 - qpx*s0;  qy = qy*c1 - qpy*s1;
                kx = kx*c0 - kpx*s0;  ky = ky*c1 - kpy*s1;
            } else {
                qx = qx*c0 + qpx*s0;  qy = qy*c1 + qpy*s1;
                kx = kx*c0 + kpx*s0;  ky = ky*c1 + kpy*s1;
            }
        }
        size_t o96  = ((size_t)h * NT_ + tok) * 96;
        size_t o128 = ((size_t)h * NT_ + tok) * 128;
        if (act){
            Qg[o96 + d] = f2bf(qx);  Qg[o96 + d + 1] = f2bf(qy);
            Kg[o128 + d] = f2bf(kx); Kg[o128 + d + 1] = f2bf(ky);
            Vg[o96 + d] = f2bf(vx);  Vg[o96 + d + 1] = f2bf(vy);
        } else {
            int dp = 96 + (lane - 48) * 2;     // zero K pad 96..127
            Kg[o128 + dp] = 0; Kg[o128 + dp + 1] = 0;
        }
    }
}

// ---------------------------------------------------------------- V transpose
__global__ __launch_bounds__(256) void vtrans_k(
    const u16* __restrict__ Vg, u16* __restrict__ Vtg)
{
    int h = blockIdx.y, t0 = blockIdx.x * 64;
    __shared__ u16 tile[64][104];
    int t = threadIdx.x;
    #pragma unroll
    for (int i = 0; i < 3; i++){
        int idx = i*256 + t;
        int tok = idx / 12, c = idx % 12;
        uint4 v = *(const uint4*)&Vg[((size_t)h*NT_ + t0 + tok)*96 + c*8];
        *(uint4*)&tile[tok][c*8] = v;
    }
    __syncthreads();
    #pragma unroll
    for (int i = 0; i < 3; i++){
        int idx = i*256 + t;
        int d = idx >> 3, tc = idx & 7;
        u16 vv[8];
        #pragma unroll
        for (int j = 0; j < 8; j++) vv[j] = tile[tc*8 + j][d];
        *(uint4*)&Vtg[((size_t)h*128 + d)*NT_ + t0 + tc*8] = *(uint4*)vv;
    }
    {
        int row = 96 + (t >> 3), tc = t & 7;
        u16 val = (row == 96) ? (u16)0x3F80 : (u16)0;
        u16 vv[8];
        #pragma unroll
        for (int j = 0; j < 8; j++) vv[j] = val;
        *(uint4*)&Vtg[((size_t)h*128 + row)*NT_ + t0 + tc*8] = *(uint4*)vv;
    }
}

// ---------------------------------------------------------------- flash attention (split-KV x3)
// O-partials in bf16 (pbO), row-sums l in f32 (pbL, exact). 12 KV tiles/block.
__global__ __launch_bounds__(256, 4) void attn_k(
    const u16* __restrict__ Qg, const u16* __restrict__ Kg,
    const u16* __restrict__ Vtg, u16* __restrict__ pbO, float* __restrict__ pbL)
{
    int bid = blockIdx.x;
    int kvh = bid / 576;                       // 0,1,2
    int bb  = bid % 576;
    int bid2 = (bb & 7) * 72 + (bb >> 3);      // same-XCD for all thirds
    int h = bid2 / 36;
    int q0 = (bid2 % 36) * 64;
    __shared__ u16 Ks[64*128];
    __shared__ u16 Vs[112*64];
    __shared__ u16 Ps[4][16*72];
    int t = threadIdx.x, wave = t >> 6, lane = t & 63;
    int lrow = lane & 15, lgrp = lane >> 4;
    const float C1 = (float)(0.10206207261596577 * 1.4426950408889634);
    const float C2 = (float)(-10.0 * 1.4426950408889634);

    const u16* qbase = Qg + ((size_t)h * NT_ + q0 + wave*16 + lrow) * 96;
    short8 qf[3];
    #pragma unroll
    for (int c = 0; c < 3; c++) qf[c] = *(const short8*)(qbase + c*32 + lgrp*8);

    const u16* Kbh = Kg  + (size_t)h * NT_ * 128;
    const u16* Vbh = Vtg + (size_t)h * 128 * NT_;

    int krow[4], kc_[4], vrow[4], vc_[4];
    #pragma unroll
    for (int i = 0; i < 4; i++){
        int g = wave*4 + i;
        krow[i] = g*4 + (lane >> 4);
        kc_[i]  = (lane & 15) ^ (krow[i] & 7);
        vrow[i] = g*8 + (lane >> 3);
        vc_[i]  = (lane & 7) ^ (vrow[i] & 7);
    }

    f32x4 oacc[7];
    #pragma unroll
    for (int n = 0; n < 7; n++) oacc[n] = (f32x4){0.f,0.f,0.f,0.f};

    int kt0 = kvh * 12;
    for (int kt = kt0; kt < kt0 + 12; kt++){
        __syncthreads();
        #pragma unroll
        for (int i = 0; i < 4; i++)
            gll16(Kbh + ((size_t)(kt*64 + krow[i]))*128 + kc_[i]*8,
                  &Ks[(wave*4 + i)*512 + lane*8]);
        #pragma unroll
        for (int i = 0; i < 4; i++){
            int g = wave*4 + i;
            if (g < 14)
                gll16(Vbh + (size_t)vrow[i]*NT_ + kt*64 + vc_[i]*8,
                      &Vs[g*512 + lane*8]);
        }
        __syncthreads();

        f32x4 s[4];
        #pragma unroll
        for (int nt = 0; nt < 4; nt++){
            s[nt] = (f32x4){0.f,0.f,0.f,0.f};
            #pragma unroll
            for (int c = 0; c < 3; c++){
                int pc = ((c*4 + lgrp) ^ (lrow & 7)) * 8;
                short8 kf = *(const short8*)&Ks[(nt*16 + lrow)*128 + pc];
                s[nt] = __builtin_amdgcn_mfma_f32_16x16x32_bf16(kf, qf[c], s[nt], 0,0,0);
            }
        }
        // P = exp2(s*C1 + C2) -> bf16 via packed RNE convert (v_cvt_pk_bf16_f32)
        #pragma unroll
        for (int nt = 0; nt < 4; nt++){
            float e0 = exp2f(fmaf(s[nt][0], C1, C2));
            float e1 = exp2f(fmaf(s[nt][1], C1, C2));
            float e2 = exp2f(fmaf(s[nt][2], C1, C2));
            float e3 = exp2f(fmaf(s[nt][3], C1, C2));
            float2 f01; f01.x = e0; f01.y = e1;
            float2 f23; f23.x = e2; f23.y = e3;
            __hip_bfloat162 h0 = __float22bfloat162_rn(f01);
            __hip_bfloat162 h1 = __float22bfloat162_rn(f23);
            uint2 pk;
            pk.x = *reinterpret_cast<u32*>(&h0);
            pk.y = *reinterpret_cast<u32*>(&h1);
            *(uint2*)&Ps[wave][lrow*72 + nt*16 + lgrp*4] = pk;
        }
        #pragma unroll
        for (int kc2 = 0; kc2 < 2; kc2++){
            short8 pf = *(const short8*)&Ps[wave][lrow*72 + kc2*32 + lgrp*8];
            #pragma unroll
            for (int n = 0; n < 7; n++){
                int pc = ((kc2*4 + lgrp) ^ (lrow & 7)) * 8;
                short8 vf = *(const short8*)&Vs[(n*16 + lrow)*64 + pc];
                oacc[n] = __builtin_amdgcn_mfma_f32_16x16x32_bf16(pf, vf, oacc[n], 0,0,0);
            }
        }
    }

    // O partials -> bf16 [64][96]; l -> f32 [64]
    u16* po = pbO + ((size_t)(bid2*3 + kvh)) * (64*96);
    #pragma unroll
    for (int n = 0; n < 6; n++){
        #pragma unroll
        for (int r = 0; r < 4; r++){
            int row = wave*16 + lgrp*4 + r;
            po[(size_t)row * 96 + n*16 + lrow] = f2bf(oacc[n][r]);
        }
    }
    if (lrow == 0){
        float* pl = pbL + ((size_t)(bid2*3 + kvh)) * 64;
        #pragma unroll
        for (int r = 0; r < 4; r++)
            pl[wave*16 + lgrp*4 + r] = oacc[6][r];
    }
}

// combine thirds: Og = (o0+o1+o2)/(l0+l1+l2)   (vectorized u16x8)
__global__ __launch_bounds__(256) void attncomb_k(
    const u16* __restrict__ pbO, const float* __restrict__ pbL,
    u16* __restrict__ Og)
{
    int cid = blockIdx.x;              // 0..575 == bid2
    int h = cid / 36, q0 = (cid % 36) * 64;
    const u16* o0 = pbO + ((size_t)(cid*3 + 0)) * (64*96);
    const u16* o1 = pbO + ((size_t)(cid*3 + 1)) * (64*96);
    const u16* o2 = pbO + ((size_t)(cid*3 + 2)) * (64*96);
    const float* l0 = pbL + ((size_t)(cid*3 + 0)) * 64;
    const float* l1 = pbL + ((size_t)(cid*3 + 1)) * 64;
    const float* l2 = pbL + ((size_t)(cid*3 + 2)) * 64;
    for (int e = threadIdx.x; e < 64*12; e += 256){
        int row = e / 12, ch = e % 12;
        float inv = 1.f / (l0[row] + l1[row] + l2[row]);
        short8 a = *(const short8*)&o0[(size_t)row*96 + ch*8];
        short8 b = *(const short8*)&o1[(size_t)row*96 + ch*8];
        short8 c = *(const short8*)&o2[(size_t)row*96 + ch*8];
        u16 ov[8];
        #pragma unroll
        for (int j = 0; j < 8; j++)
            ov[j] = f2bf((bf2f((u16)a[j]) + bf2f((u16)b[j]) + bf2f((u16)c[j])) * inv);
        *(uint4*)&Og[(size_t)(q0 + row) * D_ + h*HD_ + ch*8] = *(uint4*)ov;
    }
}

// ---------------------------------------------------------------- launcher
extern "C" void kernel_launch(void* const* d_in, const int* in_sizes, int n_in,
                              void* d_out, int out_size, void* d_ws, size_t ws_size,
                              hipStream_t stream)
{
    const float* x        = (const float*)d_in[0];
    const float* y        = (const float*)d_in[1];
    const float* tt       = (const float*)d_in[2];
    const int*   pos      = (const int*)  d_in[3];
    const float* w_mod_x  = (const float*)d_in[4];
    const float* b_mod_x  = (const float*)d_in[5];
    const float* w_mod_y  = (const float*)d_in[6];
    const float* b_mod_y  = (const float*)d_in[7];
    const float* w_qkv_x  = (const float*)d_in[8];
    const float* b_qkv_x  = (const float*)d_in[9];
    const float* w_qkv_y  = (const float*)d_in[10];
    const float* b_qkv_y  = (const float*)d_in[11];
    const float* qn_x     = (const float*)d_in[12];
    const float* kn_x     = (const float*)d_in[13];
    const float* qn_y     = (const float*)d_in[14];
    const float* kn_y     = (const float*)d_in[15];
    const float* w_proj_x = (const float*)d_in[16];
    const float* b_proj_x = (const float*)d_in[17];
    const float* w_proj_y = (const float*)d_in[18];
    const float* b_proj_y = (const float*)d_in[19];
    const float* w1_x     = (const float*)d_in[20];
    const float* w2_x     = (const float*)d_in[21];
    const float* w3_x     = (const float*)d_in[22];
    const float* w1_y     = (const float*)d_in[23];
    const float* w2_y     = (const float*)d_in[24];
    const float* w3_y     = (const float*)d_in[25];
    float* dout = (float*)d_out;

    char* ws = (char*)d_ws;
    size_t off = 0;
    float* modx   = (float*)(ws + off); off += (size_t)(6*D_) * 4;
    float* mody   = (float*)(ws + off); off += (size_t)(6*D_) * 4;
    u16*   a      = (u16*)  (ws + off); off += (size_t)NT_ * D_ * 2;        // 7.08 MB
    u16*   arena  = (u16*)  (ws + off); off += (size_t)2 * D_ * FF_ * 2;    // 37.75 MB
    u16*   r1     = (u16*)  (ws + off); off += (size_t)NT_ * FF_ * 2;       // 28.31 MB
    u16*   r2     = (u16*)  (ws + off); off += ((size_t)3*96 + 128) * H_ * NT_ * 2; // 30.72 MB
    float* x1     = (float*)(ws + off); off += (size_t)NT_ * D_ * 4;        // 14.16 MB
    u16*   Vtg    = (u16*)  (ws + off); off += (size_t)H_ * 128 * NT_ * 2;  // 9.44 MB

    // region overlays (liveness-checked):
    float* pmod   = (float*)arena;                        // modvec partials
    u16*   attnO  = arena;                                // attn O partials 21.2 MB
    float* attnL  = (float*)(arena + (size_t)1728*64*96); // attn l partials 0.44 MB
    u16*   qkvraw = r1;
    u16*   hs     = r1;
    float* p0     = (float*)r1;
    u16*   Qb     = r2;
    u16*   Kb     = r2 + (size_t)H_ * NT_ * 96;            // padded [tok][128]
    u16*   Vb     = r2 + (size_t)H_ * NT_ * (96 + 128);
    u16*   Ob     = r2 + (size_t)H_ * NT_ * (2*96 + 128);
    u16*   hb     = r2;

    const size_t qkvW  = (size_t)D_ * (3*D_);
    const size_t projW = (size_t)D_ * D_;
    const size_t ffW   = (size_t)D_ * FF_;

    // 1) modulation vectors (split-K x16) + LN/mod1
    modvec2_k<<<dim3(72, 16), 256, 0, stream>>>(tt, w_mod_x, w_mod_y, pmod);
    reducemod_k<<<72, 256, 0, stream>>>(pmod, b_mod_x, b_mod_y, modx, mody);
    lnmod_k<<<NT_, 256, 0, stream>>>(x, y, modx, mody, 0, a);
    // 2) qkv (256^2)
    transpose_k<<<dim3(48*144, 2), 256, 0, stream>>>(w_qkv_x, w_qkv_y, arena, arena + qkvW, D_, 3*D_);
    gemm3_k<0><<<9*18, 512, 0, stream>>>(a, arena, arena + qkvW, b_qkv_x, b_qkv_y,
        nullptr, qkvraw, 3*D_, D_, 9, 18);
    // 3) RMS + RoPE + reshape (K padded 128); V transpose
    qkvpost_k<<<NT_, 256, 0, stream>>>(qkvraw, pos, qn_x, kn_x, qn_y, kn_y, Qb, Kb, Vb);
    vtrans_k<<<dim3(36, 16), 256, 0, stream>>>(Vb, Vtg);
    // 4) attention split-KV x3 -> bf16 O partials + f32 l, combine -> Ob
    attn_k<<<1728, 256, 0, stream>>>(Qb, Kb, Vtg, attnO, attnL);
    attncomb_k<<<576, 256, 0, stream>>>(attnO, attnL, Ob);
    // 5) proj + residual -> x1
    transpose_k<<<dim3(48*48, 2), 256, 0, stream>>>(w_proj_x, w_proj_y, arena, arena + projW, D_, D_);
    gemm2_k<1><<<18*12, 256, 0, stream>>>(Ob, D_, arena, arena + projW, D_,
        b_proj_x, b_proj_y, x, y - (size_t)NX_*D_, modx + 2*D_, mody + 2*D_,
        x1, D_, D_, 12, 1);
    // 6) LN/mod2
    lnmod_k<<<NT_, 256, 0, stream>>>(x1, x1 + (size_t)NX_*D_, modx, mody, 3*D_, a);
    // 7) ffn w1 -> silu -> hs (256^2)
    transpose_k<<<dim3(48*192, 2), 256, 0, stream>>>(w1_x, w1_y, arena, arena + ffW, D_, FF_);
    gemm3_k<2><<<9*24, 512, 0, stream>>>(a, arena, arena + ffW, nullptr, nullptr,
        nullptr, hs, FF_, D_, 9, 24);
    // 8) ffn w2 * hs -> hb (256^2)
    transpose_k<<<dim3(48*192, 2), 256, 0, stream>>>(w2_x, w2_y, arena, arena + ffW, D_, FF_);
    gemm3_k<3><<<9*24, 512, 0, stream>>>(a, arena, arena + ffW, nullptr, nullptr,
        hs, hb, FF_, D_, 9, 24);
    // 9) w3 split-K x2 -> partials, fused reduce -> d_out
    transpose_k<<<dim3(192*48, 2), 256, 0, stream>>>(w3_x, w3_y, arena, arena + ffW, FF_, D_);
    gemm2_k<5><<<18*12*2, 256, 0, stream>>>(hb, FF_, arena, arena + ffW, FF_,
        nullptr, nullptr, nullptr, nullptr, nullptr, nullptr,
        p0, D_, 3072, 12, 2);
    reduce_k<<<(NT_*D_/4)/256, 256, 0, stream>>>(p0, x1, modx, mody, dout);
    (void)in_sizes; (void)n_in; (void)out_size; (void)ws_size;
}